// Round 11
// baseline (1579.365 us; speedup 1.0000x reference)
//
#include <hip/hip_runtime.h>
#include <hip/hip_cooperative_groups.h>
#include <math.h>

namespace cg = cooperative_groups;

// Problem constants
constexpr int Bc = 8, Tc = 256, Dc = 512, Mc = 128, Lc = 4, Vc = 32000;
constexpr int Rc = Bc * Tc;          // 2048 rows
constexpr int Hc = 4 * Dc;           // 2048 hidden

typedef __bf16 bf16_t;
typedef __bf16 bf16x8 __attribute__((ext_vector_type(8)));
typedef float f32x4 __attribute__((ext_vector_type(4)));
static_assert(sizeof(bf16x8) == 16, "bf16x8 must be 16B");

#define DEV __device__ __forceinline__

DEV float wred64(float x) {
#pragma unroll
  for (int o = 32; o; o >>= 1) x += __shfl_xor(x, o);
  return x;
}

// ---------------------------------------------------------------- merged preamble
__global__ __launch_bounds__(256) void pre_k(
    const float* __restrict__ center, bf16_t* __restrict__ cen_bf,
    const float* __restrict__ w1, bf16_t* __restrict__ w1_bf,
    const float* __restrict__ w2, bf16_t* __restrict__ w2_bf,
    const float* __restrict__ wo, bf16_t* __restrict__ wo_bf,
    const float* __restrict__ wk, const float* __restrict__ wq,
    const float* __restrict__ wv, const float* __restrict__ wgw,
    const float* __restrict__ wgf, bf16_t* __restrict__ wkqv_bf,
    const float* __restrict__ bk, const float* __restrict__ bq,
    const float* __restrict__ bv, const float* __restrict__ bgw,
    const float* __restrict__ bgf, float* __restrict__ bkqv,
    const int* __restrict__ idx, const float* __restrict__ g1,
    const float* __restrict__ b1, float* __restrict__ x,
    bf16_t* __restrict__ xn) {
  int blk = blockIdx.x, t = threadIdx.x;
  if (blk < 12224) {
    const float* src; bf16_t* dst; int base;
    if (blk < 8000)       { src = center; dst = cen_bf; base = blk; }
    else if (blk < 10048) { src = w1; dst = w1_bf; base = blk - 8000; }
    else if (blk < 12096) { src = w2; dst = w2_bf; base = blk - 10048; }
    else                  { src = wo; dst = wo_bf; base = blk - 12096; }
    size_t i = (size_t)base * 2048 + (size_t)t * 8;
    float4 a = *(const float4*)(src + i);
    float4 b = *(const float4*)(src + i + 4);
    bf16_t o[8] = {(bf16_t)a.x, (bf16_t)a.y, (bf16_t)a.z, (bf16_t)a.w,
                   (bf16_t)b.x, (bf16_t)b.y, (bf16_t)b.z, (bf16_t)b.w};
    *(bf16x8*)(dst + i) = *(bf16x8*)o;
  } else if (blk < 13248) {
    int row = (blk - 12224) * 2 + (t >> 7);
    int t7 = t & 127;
    int lyr = row >> 9, o = row & 511;
    const float* src = nullptr;
    if (o < 128) src = wk + ((size_t)lyr * 128 + o) * Dc;
    else if (o < 256) src = wq + ((size_t)lyr * 128 + (o - 128)) * Dc;
    else if (o < 384) src = wv + ((size_t)lyr * 128 + (o - 256)) * Dc;
    else if (o == 384) src = wgw + (size_t)lyr * Dc;
    else if (o == 385) src = wgf + (size_t)lyr * Dc;
    bf16_t* dst = wkqv_bf + (size_t)row * Dc + t7 * 4;
    if (src) {
      float4 v = ((const float4*)src)[t7];
      dst[0] = (bf16_t)v.x; dst[1] = (bf16_t)v.y; dst[2] = (bf16_t)v.z; dst[3] = (bf16_t)v.w;
    } else {
      dst[0] = dst[1] = dst[2] = dst[3] = (bf16_t)0.f;
    }
  } else if (blk < 13256) {
    int i = (blk - 13248) * 256 + t;
    int lyr = i >> 9, o = i & 511;
    float v = 0.f;
    if (o < 128) v = bk[lyr * 128 + o];
    else if (o < 256) v = bq[lyr * 128 + o - 128];
    else if (o < 384) v = bv[lyr * 128 + o - 256];
    else if (o == 384) v = bgw[lyr];
    else if (o == 385) v = bgf[lyr];
    bkqv[i] = v;
  } else {
    int r = (blk - 13256) * 4 + (t >> 6);
    int t6 = t & 63;
    const float4* row = (const float4*)(center + (size_t)idx[r] * Dc);
    float xv[8];
    *(float4*)&xv[0] = row[2 * t6];
    *(float4*)&xv[4] = row[2 * t6 + 1];
    float4* xrow = (float4*)(x + (size_t)r * Dc);
    xrow[2 * t6] = *(float4*)&xv[0];
    xrow[2 * t6 + 1] = *(float4*)&xv[4];
    float s = 0.f, ss = 0.f;
#pragma unroll
    for (int e = 0; e < 8; ++e) { s += xv[e]; ss += xv[e] * xv[e]; }
    s = wred64(s); ss = wred64(ss);
    float mu = s * (1.f / Dc);
    float inv = 1.f / sqrtf(ss * (1.f / Dc) - mu * mu + 1e-5f);
    float gg[8], bb[8];
    *(float4*)&gg[0] = ((const float4*)g1)[2 * t6];
    *(float4*)&gg[4] = ((const float4*)g1)[2 * t6 + 1];
    *(float4*)&bb[0] = ((const float4*)b1)[2 * t6];
    *(float4*)&bb[4] = ((const float4*)b1)[2 * t6 + 1];
    bf16_t ob[8];
#pragma unroll
    for (int e = 0; e < 8; ++e) ob[e] = (bf16_t)((xv[e] - mu) * inv * gg[e] + bb[e]);
    *(bf16x8*)(xn + (size_t)r * Dc + t6 * 8) = *(bf16x8*)ob;
  }
}

// ---------------------------------------------------------------- MFMA helpers
DEV int swz_eoff(int row, int kbyte) {
  return row * 64 + ((kbyte ^ ((row & 7) << 4)) >> 1);
}

enum { A_NONE = 0, A_GELU = 2 };

template <int ACT, bool ACCUM, bool SCALE, bool OBF16>
DEV void mm_epi(f32x4 (&acc)[4][4], int bm, int bn, int wm, int wn, int lhi, int l15,
                void* Cv, const float* bias, int ldc, long long sC, int z, float sc) {
  float* Cf = (float*)Cv;
  bf16_t* Cb = (bf16_t*)Cv;
#pragma unroll
  for (int m = 0; m < 4; ++m) {
#pragma unroll
    for (int n = 0; n < 4; ++n) {
#pragma unroll
      for (int q = 0; q < 4; ++q) {
        int row = bm + wm + m * 16 + lhi * 4 + q;   // C/D: col=lane&15, row=(lane>>4)*4+reg (m89)
        int col = bn + wn + n * 16 + l15;
        float val = acc[m][n][q];
        if (bias) val += bias[col];
        if (ACT == A_GELU) {
          val = 0.5f * val * (1.f + erff(val * 0.70710678118654752f));
        }
        if (SCALE) val *= sc;
        size_t off = (size_t)z * sC + (size_t)row * ldc + col;
        if (OBF16) {
          Cb[off] = (bf16_t)val;
        } else if (SCALE) {
          __builtin_nontemporal_store(val, Cf + off);   // logits: write-once
        } else {
          if (ACCUM) val += Cf[off];
          Cf[off] = val;
        }
      }
    }
  }
}

// ---------------------------------------------------------------- logits GEMM: single-buffer, 3 blk/CU
template <int ACT, bool ACCUM, bool SCALE, bool OBF16, bool SWZ>
__global__ __launch_bounds__(256, 3) void mm_k(
    const bf16_t* __restrict__ A, const bf16_t* __restrict__ B, void* __restrict__ Cv,
    const float* __restrict__ bias, int K, int lda, int ldb, int ldc,
    long long sA, long long sB, long long sC,
    const float* __restrict__ scale_ptr, float scale_const) {
  __shared__ bf16_t As[128 * 64];
  __shared__ bf16_t Bs[128 * 64];
  const int z = blockIdx.z;
  int ntile, mtile;
  if (SWZ) {
    int nwg = gridDim.x * gridDim.y;           // logits: 4000, %8==0
    int orig = blockIdx.y * gridDim.x + blockIdx.x;
    int q = nwg >> 3;
    int id = (orig & 7) * q + (orig >> 3);     // bijective XCD chunking
    mtile = id % gridDim.y;
    ntile = id / gridDim.y;
  } else {
    ntile = blockIdx.x;
    mtile = blockIdx.y;
  }
  const int bm = mtile * 128, bn = ntile * 128;
  A += (size_t)z * sA;
  B += (size_t)z * sB;
  const int tid = threadIdx.x, w = tid >> 6, l = tid & 63;
  const int wm = (w >> 1) * 64, wn = (w & 1) * 64;
  const int l15 = l & 15, lhi = l >> 4;

  int rS[4], koS[4];
#pragma unroll
  for (int i = 0; i < 4; ++i) {
    int c = tid + i * 256;
    int r = c >> 3, kb = (c & 7) << 4;
    rS[i] = r;
    koS[i] = (kb ^ ((r & 7) << 4)) >> 1;
  }
  const bf16_t* Ab = A + (size_t)bm * lda;
  const bf16_t* Bb = B + (size_t)bn * ldb;

  f32x4 acc[4][4] = {};
  for (int k0 = 0; k0 < K; k0 += 64) {
#pragma unroll
    for (int i = 0; i < 4; ++i) {
      __builtin_amdgcn_global_load_lds(
          (const __attribute__((address_space(1))) void*)(Ab + (size_t)rS[i] * lda + k0 + koS[i]),
          (__attribute__((address_space(3))) void*)(As + ((size_t)w * 64 + i * 256) * 8), 16, 0, 0);
    }
#pragma unroll
    for (int i = 0; i < 4; ++i) {
      __builtin_amdgcn_global_load_lds(
          (const __attribute__((address_space(1))) void*)(Bb + (size_t)rS[i] * ldb + k0 + koS[i]),
          (__attribute__((address_space(3))) void*)(Bs + ((size_t)w * 64 + i * 256) * 8), 16, 0, 0);
    }
    __syncthreads();
    bf16x8 af[2][4], bf_[2][4];
#pragma unroll
    for (int h = 0; h < 2; ++h) {
#pragma unroll
      for (int m = 0; m < 4; ++m) {
        int row = wm + m * 16 + l15;
        af[h][m] = *(const bf16x8*)(As + swz_eoff(row, (h << 6) | (lhi << 4)));
        int col = wn + m * 16 + l15;
        bf_[h][m] = *(const bf16x8*)(Bs + swz_eoff(col, (h << 6) | (lhi << 4)));
      }
    }
#pragma unroll
    for (int h = 0; h < 2; ++h)
#pragma unroll
      for (int m = 0; m < 4; ++m)
#pragma unroll
        for (int n = 0; n < 4; ++n)
          acc[m][n] = __builtin_amdgcn_mfma_f32_16x16x32_bf16(af[h][m], bf_[h][n], acc[m][n], 0, 0, 0);
    __syncthreads();
  }
  float sc = SCALE ? scale_const * scale_ptr[0] : 1.f;
  mm_epi<ACT, ACCUM, SCALE, OBF16>(acc, bm, bn, wm, wn, lhi, l15, Cv, bias, ldc, sC, z, sc);
}

// ---------------------------------------------------------------- small GEMM: 2-phase dbuf (fallback)
template <int ACT, bool ACCUM, bool OBF16>
__global__ __launch_bounds__(256, 2) void mms_k(
    const bf16_t* __restrict__ A, const bf16_t* __restrict__ B, void* __restrict__ Cv,
    const float* __restrict__ bias, int K, int lda, int ldb, int ldc,
    long long sA, long long sB, long long sC) {
  __shared__ bf16_t As[2 * 128 * 64];
  __shared__ bf16_t Bs[2 * 128 * 64];
  const int z = blockIdx.z;
  const int bm = blockIdx.y * 128, bn = blockIdx.x * 128;
  A += (size_t)z * sA;
  B += (size_t)z * sB;
  const int tid = threadIdx.x, w = tid >> 6, l = tid & 63;
  const int wm = (w >> 1) * 64, wn = (w & 1) * 64;
  const int l15 = l & 15, lhi = l >> 4;

  int rS[4], koS[4];
#pragma unroll
  for (int i = 0; i < 4; ++i) {
    int c = tid + i * 256;
    int r = c >> 3, kb = (c & 7) << 4;
    rS[i] = r;
    koS[i] = (kb ^ ((r & 7) << 4)) >> 1;
  }
  const bf16_t* Ab = A + (size_t)bm * lda;
  const bf16_t* Bb = B + (size_t)bn * ldb;

  auto STAGE = [&](int buf, int k0) {
    bf16_t* Ad = As + buf * 8192;
    bf16_t* Bd = Bs + buf * 8192;
#pragma unroll
    for (int i = 0; i < 4; ++i)
      __builtin_amdgcn_global_load_lds(
          (const __attribute__((address_space(1))) void*)(Ab + (size_t)rS[i] * lda + k0 + koS[i]),
          (__attribute__((address_space(3))) void*)(Ad + ((size_t)w * 64 + i * 256) * 8), 16, 0, 0);
#pragma unroll
    for (int i = 0; i < 4; ++i)
      __builtin_amdgcn_global_load_lds(
          (const __attribute__((address_space(1))) void*)(Bb + (size_t)rS[i] * ldb + k0 + koS[i]),
          (__attribute__((address_space(3))) void*)(Bd + ((size_t)w * 64 + i * 256) * 8), 16, 0, 0);
  };

  f32x4 acc[4][4] = {};
  const int nt = K >> 6;
  STAGE(0, 0);
  __syncthreads();
  int cur = 0;
  for (int t = 0; t < nt; ++t) {
    if (t + 1 < nt) STAGE(cur ^ 1, (t + 1) << 6);
    const bf16_t* Ar = As + cur * 8192;
    const bf16_t* Br = Bs + cur * 8192;
    bf16x8 af[2][4], bf_[2][4];
#pragma unroll
    for (int h = 0; h < 2; ++h) {
#pragma unroll
      for (int m = 0; m < 4; ++m) {
        int row = wm + m * 16 + l15;
        af[h][m] = *(const bf16x8*)(Ar + swz_eoff(row, (h << 6) | (lhi << 4)));
        int col = wn + m * 16 + l15;
        bf_[h][m] = *(const bf16x8*)(Br + swz_eoff(col, (h << 6) | (lhi << 4)));
      }
    }
#pragma unroll
    for (int h = 0; h < 2; ++h)
#pragma unroll
      for (int m = 0; m < 4; ++m)
#pragma unroll
        for (int n = 0; n < 4; ++n)
          acc[m][n] = __builtin_amdgcn_mfma_f32_16x16x32_bf16(af[h][m], bf_[h][n], acc[m][n], 0, 0, 0);
    __syncthreads();
    cur ^= 1;
  }
  mm_epi<ACT, ACCUM, false, OBF16>(acc, bm, bn, wm, wn, lhi, l15, Cv, bias, ldc, sC, z, 1.f);
}

// ---------------------------------------------------------------- LayerNorm -> bf16 (fallback ln2)
__global__ __launch_bounds__(64) void ln_k(const float* __restrict__ in,
                                           const float* __restrict__ g,
                                           const float* __restrict__ b,
                                           bf16_t* __restrict__ out) {
  int r = blockIdx.x, t = threadIdx.x;
  const float4* row = (const float4*)(in + (size_t)r * Dc);
  float xv[8];
  *(float4*)&xv[0] = row[2 * t];
  *(float4*)&xv[4] = row[2 * t + 1];
  float s = 0.f, ss = 0.f;
#pragma unroll
  for (int e = 0; e < 8; ++e) { s += xv[e]; ss += xv[e] * xv[e]; }
  s = wred64(s); ss = wred64(ss);
  float mu = s * (1.f / Dc);
  float inv = 1.f / sqrtf(ss * (1.f / Dc) - mu * mu + 1e-5f);
  float gg[8], bb[8];
  *(float4*)&gg[0] = ((const float4*)g)[2 * t];
  *(float4*)&gg[4] = ((const float4*)g)[2 * t + 1];
  *(float4*)&bb[0] = ((const float4*)b)[2 * t];
  *(float4*)&bb[4] = ((const float4*)b)[2 * t + 1];
  bf16_t ob[8];
#pragma unroll
  for (int e = 0; e < 8; ++e) ob[e] = (bf16_t)((xv[e] - mu) * inv * gg[e] + bb[e]);
  *(bf16x8*)(out + (size_t)r * Dc + t * 8) = *(bf16x8*)ob;
}

// ---------------------------------------------------------------- split-K reduce + residual + LN (fallback)
__global__ __launch_bounds__(64) void redln_k(const float* __restrict__ part,
                                              const float* __restrict__ bias,
                                              float* __restrict__ x,
                                              const float* __restrict__ g,
                                              const float* __restrict__ b,
                                              bf16_t* __restrict__ xn) {
  int r = blockIdx.x, t = threadIdx.x;
  const float4* xr = (const float4*)(x + (size_t)r * Dc);
  const float4* p0 = (const float4*)(part + (size_t)r * Dc);
  const float4* p1 = (const float4*)(part + (size_t)(Rc + r) * Dc);
  const float4* bb4 = (const float4*)bias;
  float xv[8];
#pragma unroll
  for (int j = 0; j < 2; ++j) {
    float4 a = xr[2 * t + j], q = p0[2 * t + j], w = p1[2 * t + j], c = bb4[2 * t + j];
    xv[4 * j + 0] = a.x + q.x + w.x + c.x;
    xv[4 * j + 1] = a.y + q.y + w.y + c.y;
    xv[4 * j + 2] = a.z + q.z + w.z + c.z;
    xv[4 * j + 3] = a.w + q.w + w.w + c.w;
  }
  float4* xw = (float4*)(x + (size_t)r * Dc);
  xw[2 * t] = *(float4*)&xv[0];
  xw[2 * t + 1] = *(float4*)&xv[4];
  float s = 0.f, ss = 0.f;
#pragma unroll
  for (int e = 0; e < 8; ++e) { s += xv[e]; ss += xv[e] * xv[e]; }
  s = wred64(s); ss = wred64(ss);
  float mu = s * (1.f / Dc);
  float inv = 1.f / sqrtf(ss * (1.f / Dc) - mu * mu + 1e-5f);
  float gg[8], bv[8];
  *(float4*)&gg[0] = ((const float4*)g)[2 * t];
  *(float4*)&gg[4] = ((const float4*)g)[2 * t + 1];
  *(float4*)&bv[0] = ((const float4*)b)[2 * t];
  *(float4*)&bv[4] = ((const float4*)b)[2 * t + 1];
  bf16_t ob[8];
#pragma unroll
  for (int e = 0; e < 8; ++e) ob[e] = (bf16_t)((xv[e] - mu) * inv * gg[e] + bv[e]);
  *(bf16x8*)(xn + (size_t)r * Dc + t * 8) = *(bf16x8*)ob;
}

// ---------------------------------------------------------------- kqv GEMM + prep (fallback kernel)
__global__ __launch_bounds__(256) void kqvprep_k(
    const bf16_t* __restrict__ A, const bf16_t* __restrict__ B,
    const float* __restrict__ bias,
    bf16_t* __restrict__ kb, bf16_t* __restrict__ qb,
    bf16_t* __restrict__ kt, bf16_t* __restrict__ vt,
    float* __restrict__ gwb, float* __restrict__ gfb) {
  __shared__ bf16_t As[2 * 128 * 64];
  __shared__ bf16_t Bs[2 * 128 * 64];
  __shared__ float tile[128 * 129];
  __shared__ float rno[128];
  const int ntile = blockIdx.x, mtile = blockIdx.y;
  const int bm = mtile * 128, bn = ntile * 128;
  const int tid = threadIdx.x, w = tid >> 6, l = tid & 63;
  const int wm = (w >> 1) * 64, wn = (w & 1) * 64;
  const int l15 = l & 15, lhi = l >> 4;

  int rS[4], koS[4];
#pragma unroll
  for (int i = 0; i < 4; ++i) {
    int c = tid + i * 256;
    int r = c >> 3, kbb = (c & 7) << 4;
    rS[i] = r;
    koS[i] = (kbb ^ ((r & 7) << 4)) >> 1;
  }
  const bf16_t* Ab = A + (size_t)bm * Dc;
  const bf16_t* Bb = B + (size_t)bn * Dc;

  auto STAGE = [&](int buf, int k0) {
    bf16_t* Ad = As + buf * 8192;
    bf16_t* Bd = Bs + buf * 8192;
#pragma unroll
    for (int i = 0; i < 4; ++i)
      __builtin_amdgcn_global_load_lds(
          (const __attribute__((address_space(1))) void*)(Ab + (size_t)rS[i] * Dc + k0 + koS[i]),
          (__attribute__((address_space(3))) void*)(Ad + ((size_t)w * 64 + i * 256) * 8), 16, 0, 0);
#pragma unroll
    for (int i = 0; i < 4; ++i)
      __builtin_amdgcn_global_load_lds(
          (const __attribute__((address_space(1))) void*)(Bb + (size_t)rS[i] * Dc + k0 + koS[i]),
          (__attribute__((address_space(3))) void*)(Bd + ((size_t)w * 64 + i * 256) * 8), 16, 0, 0);
  };

  f32x4 acc[4][4] = {};
  STAGE(0, 0);
  __syncthreads();
  int cur = 0;
  for (int t = 0; t < 8; ++t) {
    if (t + 1 < 8) STAGE(cur ^ 1, (t + 1) << 6);
    const bf16_t* Ar = As + cur * 8192;
    const bf16_t* Br = Bs + cur * 8192;
    bf16x8 af[2][4], bf_[2][4];
#pragma unroll
    for (int h = 0; h < 2; ++h) {
#pragma unroll
      for (int m = 0; m < 4; ++m) {
        int row = wm + m * 16 + l15;
        af[h][m] = *(const bf16x8*)(Ar + swz_eoff(row, (h << 6) | (lhi << 4)));
        int col = wn + m * 16 + l15;
        bf_[h][m] = *(const bf16x8*)(Br + swz_eoff(col, (h << 6) | (lhi << 4)));
      }
    }
#pragma unroll
    for (int h = 0; h < 2; ++h)
#pragma unroll
      for (int m = 0; m < 4; ++m)
#pragma unroll
        for (int n = 0; n < 4; ++n)
          acc[m][n] = __builtin_amdgcn_mfma_f32_16x16x32_bf16(af[h][m], bf_[h][n], acc[m][n], 0, 0, 0);
    __syncthreads();
    cur ^= 1;
  }

  if (ntile == 3) {
#pragma unroll
    for (int m = 0; m < 4; ++m)
#pragma unroll
      for (int n = 0; n < 4; ++n)
#pragma unroll
        for (int q = 0; q < 4; ++q) {
          int c = wn + n * 16 + l15;
          if (c <= 1) {
            int row = bm + wm + m * 16 + lhi * 4 + q;
            float val = acc[m][n][q] + bias[384 + c];
            if (c == 0) gwb[row] = 1.f / (1.f + expf(-val));
            else gfb[row] = 0.9f / (1.f + expf(-val));
          }
        }
    return;
  }
#pragma unroll
  for (int m = 0; m < 4; ++m)
#pragma unroll
    for (int n = 0; n < 4; ++n)
#pragma unroll
      for (int q = 0; q < 4; ++q) {
        int row = wm + m * 16 + lhi * 4 + q;
        int col = wn + n * 16 + l15;
        float val = acc[m][n][q] + bias[ntile * 128 + col];
        if (ntile == 2) val = tanhf(val);
        tile[row * 129 + col] = val;
      }
  __syncthreads();

  const int b = bm >> 8;
  const int s0 = bm & 255;

  if (ntile <= 1) {
    int row = tid >> 1, off = (tid & 1) * 64;
    float ss = 0.f;
#pragma unroll
    for (int e = 0; e < 64; ++e) { float v = tile[row * 129 + off + e]; ss += v * v; }
    ss += __shfl_xor(ss, 1);
    if (!(tid & 1)) rno[row] = 1.f / fmaxf(sqrtf(ss), 1e-12f);
    __syncthreads();
    float rn = rno[row];
    bf16_t* dst = (ntile == 0 ? kb : qb) + (size_t)(bm + row) * Mc + off;
#pragma unroll
    for (int j = 0; j < 8; ++j) {
      bf16_t o[8];
#pragma unroll
      for (int e = 0; e < 8; ++e) o[e] = (bf16_t)(tile[row * 129 + off + j * 8 + e] * rn);
      *(bf16x8*)(dst + j * 8) = *(bf16x8*)o;
    }
  }
  if (ntile == 0 || ntile == 2) {
    int d = tid >> 1, s8 = (tid & 1) * 64;
    bf16_t* dst = (ntile == 0 ? kt : vt) + ((size_t)b * Mc + d) * Tc + s0 + s8;
#pragma unroll
    for (int j = 0; j < 8; ++j) {
      bf16_t o[8];
#pragma unroll
      for (int e = 0; e < 8; ++e) {
        int s = s8 + j * 8 + e;
        float v = tile[s * 129 + d];
        if (ntile == 0) v *= rno[s];
        o[e] = (bf16_t)v;
      }
      *(bf16x8*)(dst + j * 8) = *(bf16x8*)o;
    }
  }
}

// ---------------------------------------------------------------- fused attention (fallback kernel)
__global__ __launch_bounds__(256) void attn_k(
    const bf16_t* __restrict__ qb, const bf16_t* __restrict__ kb,
    const bf16_t* __restrict__ vt, const bf16_t* __restrict__ kt,
    const float* __restrict__ gwb, const float* __restrict__ gfb,
    bf16_t* __restrict__ rd, float* __restrict__ states) {
  __shared__ bf16_t Ps[128 * 256];
  __shared__ float sc[Tc], sgw[Tc], sw[Tc];
  const int role = blockIdx.x, b = blockIdx.y;
  const int tid = threadIdx.x, w = tid >> 6, l = tid & 63;
  const int wm = (w >> 1) * 64, wn = (w & 1) * 64;
  const int l15 = l & 15, lhi = l >> 4;

  sc[tid] = logf(gfb[b * Tc + tid]);
  sgw[tid] = gwb[b * Tc + tid];
  __syncthreads();
  for (int o = 1; o < Tc; o <<= 1) {
    float v = (tid >= o) ? sc[tid - o] : 0.f;
    __syncthreads();
    sc[tid] += v;
    __syncthreads();
  }
  sw[tid] = sgw[tid] * expf(sc[Tc - 1] - sc[tid]);
  __syncthreads();

  if (role == 2) {
    const bf16_t* Ab = vt + (size_t)b * Mc * Tc;
    const bf16_t* Bb = kt + (size_t)b * Mc * Tc;
    f32x4 acc[4][4] = {};
#pragma unroll
    for (int ks = 0; ks < 4; ++ks) {
#pragma unroll
      for (int h = 0; h < 2; ++h) {
        int ko = ks * 64 + h * 32 + lhi * 8;
        bf16x8 af[4], bf_[4];
#pragma unroll
        for (int m = 0; m < 4; ++m) {
          bf16x8 raw = *(const bf16x8*)(Ab + (size_t)(wm + m * 16 + l15) * Tc + ko);
          bf16_t sa[8];
#pragma unroll
          for (int e = 0; e < 8; ++e) sa[e] = (bf16_t)((float)raw[e] * sw[ko + e]);
          af[m] = *(bf16x8*)sa;
        }
#pragma unroll
        for (int n = 0; n < 4; ++n)
          bf_[n] = *(const bf16x8*)(Bb + (size_t)(wn + n * 16 + l15) * Tc + ko);
#pragma unroll
        for (int m = 0; m < 4; ++m)
#pragma unroll
          for (int n = 0; n < 4; ++n)
            acc[m][n] = __builtin_amdgcn_mfma_f32_16x16x32_bf16(af[m], bf_[n], acc[m][n], 0, 0, 0);
      }
    }
#pragma unroll
    for (int m = 0; m < 4; ++m)
#pragma unroll
      for (int n = 0; n < 4; ++n)
#pragma unroll
        for (int q = 0; q < 4; ++q) {
          int row = wm + m * 16 + lhi * 4 + q;
          int col = wn + n * 16 + l15;
          __builtin_nontemporal_store(acc[m][n][q], states + ((size_t)b * Mc + row) * Mc + col);
        }
    return;
  }

  const int q0 = role * 128;
  const bf16_t* Aq = qb + (size_t)(b * Tc + q0) * Mc;
#pragma unroll 1
  for (int nt2 = 0; nt2 < 2; ++nt2) {
    const bf16_t* Bk = kb + (size_t)(b * Tc + nt2 * 128) * Mc;
    f32x4 acc[4][4] = {};
#pragma unroll
    for (int kk = 0; kk < 2; ++kk) {
#pragma unroll
      for (int h = 0; h < 2; ++h) {
        int ko = kk * 64 + h * 32 + lhi * 8;
        bf16x8 af[4], bf_[4];
#pragma unroll
        for (int m = 0; m < 4; ++m)
          af[m] = *(const bf16x8*)(Aq + (size_t)(wm + m * 16 + l15) * Mc + ko);
#pragma unroll
        for (int n = 0; n < 4; ++n)
          bf_[n] = *(const bf16x8*)(Bk + (size_t)(wn + n * 16 + l15) * Mc + ko);
#pragma unroll
        for (int m = 0; m < 4; ++m)
#pragma unroll
          for (int n = 0; n < 4; ++n)
            acc[m][n] = __builtin_amdgcn_mfma_f32_16x16x32_bf16(af[m], bf_[n], acc[m][n], 0, 0, 0);
      }
    }
#pragma unroll
    for (int m = 0; m < 4; ++m)
#pragma unroll
      for (int n = 0; n < 4; ++n)
#pragma unroll
        for (int q = 0; q < 4; ++q) {
          int tr = wm + m * 16 + lhi * 4 + q;
          int scol = nt2 * 128 + wn + n * 16 + l15;
          int tg = q0 + tr;
          float val = acc[m][n][q];
          if (scol < tg)
            val *= sgw[scol] * expf(sc[tg - 1] - sc[scol]);
          else
            val = 0.f;
          int byte = (scol * 2) ^ ((tr & 7) << 4);
          Ps[tr * 256 + (byte >> 1)] = (bf16_t)val;
        }
  }
  __syncthreads();
  {
    const bf16_t* Bb = vt + (size_t)b * Mc * Tc;
    f32x4 acc[4][4] = {};
#pragma unroll
    for (int ks = 0; ks < 4; ++ks) {
#pragma unroll
      for (int h = 0; h < 2; ++h) {
        bf16x8 af[4], bf_[4];
#pragma unroll
        for (int m = 0; m < 4; ++m) {
          int row = wm + m * 16 + l15;
          int byteA = (ks * 128 + h * 64 + lhi * 16) ^ ((row & 7) << 4);
          af[m] = *(const bf16x8*)(Ps + row * 256 + (byteA >> 1));
        }
        int ko = ks * 64 + h * 32 + lhi * 8;
#pragma unroll
        for (int n = 0; n < 4; ++n)
          bf_[n] = *(const bf16x8*)(Bb + (size_t)(wn + n * 16 + l15) * Tc + ko);
#pragma unroll
        for (int m = 0; m < 4; ++m)
#pragma unroll
          for (int n = 0; n < 4; ++n)
            acc[m][n] = __builtin_amdgcn_mfma_f32_16x16x32_bf16(af[m], bf_[n], acc[m][n], 0, 0, 0);
      }
    }
#pragma unroll
    for (int m = 0; m < 4; ++m)
#pragma unroll
      for (int n = 0; n < 4; ++n)
#pragma unroll
        for (int q = 0; q < 4; ++q) {
          int row = wm + m * 16 + lhi * 4 + q;
          int col = wn + n * 16 + l15;
          rd[(size_t)(b * Tc + q0 + row) * Mc + col] = (bf16_t)acc[m][n][q];
        }
  }
}

// ================================================================ cooperative mega-kernel stages
// LDS plan (68608 B total):
//   mm_stage : As[0,32768) Bs[32768,65536)
//   kqv_stage: GEMM loop uses As/Bs; epilogue REUSES [0,66048) as fp32 tile + rno at 66048 (+512)
//   attn_stage: Ps[0,65536) + sc/sgw/sw [65536,68608)

template <int ACT, bool ACCUM, bool OBF16>
DEV void mm_stage(char* smem, int tid, int bm, int bn, int z,
                  const bf16_t* A, const bf16_t* B, void* Cv, const float* bias,
                  int K, int lda, int ldb, int ldc,
                  long long sA, long long sB, long long sC) {
  bf16_t* As = (bf16_t*)smem;
  bf16_t* Bs = (bf16_t*)(smem + 32768);
  const int w = tid >> 6, l = tid & 63;
  const int wm = (w >> 1) * 64, wn = (w & 1) * 64;
  const int l15 = l & 15, lhi = l >> 4;
  A += (size_t)z * sA;
  B += (size_t)z * sB;
  int rS[4], koS[4];
#pragma unroll
  for (int i = 0; i < 4; ++i) {
    int c = tid + i * 256;
    int r = c >> 3, kb = (c & 7) << 4;
    rS[i] = r;
    koS[i] = (kb ^ ((r & 7) << 4)) >> 1;
  }
  const bf16_t* Ab = A + (size_t)bm * lda;
  const bf16_t* Bb = B + (size_t)bn * ldb;

  auto STAGE = [&](int buf, int k0) {
    bf16_t* Ad = As + buf * 8192;
    bf16_t* Bd = Bs + buf * 8192;
#pragma unroll
    for (int i = 0; i < 4; ++i)
      __builtin_amdgcn_global_load_lds(
          (const __attribute__((address_space(1))) void*)(Ab + (size_t)rS[i] * lda + k0 + koS[i]),
          (__attribute__((address_space(3))) void*)(Ad + ((size_t)w * 64 + i * 256) * 8), 16, 0, 0);
#pragma unroll
    for (int i = 0; i < 4; ++i)
      __builtin_amdgcn_global_load_lds(
          (const __attribute__((address_space(1))) void*)(Bb + (size_t)rS[i] * ldb + k0 + koS[i]),
          (__attribute__((address_space(3))) void*)(Bd + ((size_t)w * 64 + i * 256) * 8), 16, 0, 0);
  };

  f32x4 acc[4][4] = {};
  const int nt = K >> 6;
  STAGE(0, 0);
  __syncthreads();
  int cur = 0;
  for (int t = 0; t < nt; ++t) {
    if (t + 1 < nt) STAGE(cur ^ 1, (t + 1) << 6);
    const bf16_t* Ar = As + cur * 8192;
    const bf16_t* Br = Bs + cur * 8192;
    bf16x8 af[2][4], bf_[2][4];
#pragma unroll
    for (int h = 0; h < 2; ++h) {
#pragma unroll
      for (int m = 0; m < 4; ++m) {
        int row = wm + m * 16 + l15;
        af[h][m] = *(const bf16x8*)(Ar + swz_eoff(row, (h << 6) | (lhi << 4)));
        int col = wn + m * 16 + l15;
        bf_[h][m] = *(const bf16x8*)(Br + swz_eoff(col, (h << 6) | (lhi << 4)));
      }
    }
#pragma unroll
    for (int h = 0; h < 2; ++h)
#pragma unroll
      for (int m = 0; m < 4; ++m)
#pragma unroll
        for (int n = 0; n < 4; ++n)
          acc[m][n] = __builtin_amdgcn_mfma_f32_16x16x32_bf16(af[h][m], bf_[h][n], acc[m][n], 0, 0, 0);
    __syncthreads();
    cur ^= 1;
  }
  mm_epi<ACT, ACCUM, false, OBF16>(acc, bm, bn, wm, wn, lhi, l15, Cv, bias, ldc, sC, z, 1.f);
}

DEV void kqv_stage(char* smem, int tid, int ntile, int mtile,
                   const bf16_t* A, const bf16_t* B, const float* bias,
                   bf16_t* kb, bf16_t* qb, bf16_t* kt, bf16_t* vt,
                   float* gwb, float* gfb) {
  bf16_t* As = (bf16_t*)smem;
  bf16_t* Bs = (bf16_t*)(smem + 32768);
  float* tile = (float*)smem;                    // reused AFTER the K-loop (As/Bs dead)
  float* rno = (float*)(smem + 66048);
  const int bm = mtile * 128, bn = ntile * 128;
  const int w = tid >> 6, l = tid & 63;
  const int wm = (w >> 1) * 64, wn = (w & 1) * 64;
  const int l15 = l & 15, lhi = l >> 4;

  int rS[4], koS[4];
#pragma unroll
  for (int i = 0; i < 4; ++i) {
    int c = tid + i * 256;
    int r = c >> 3, kbb = (c & 7) << 4;
    rS[i] = r;
    koS[i] = (kbb ^ ((r & 7) << 4)) >> 1;
  }
  const bf16_t* Ab = A + (size_t)bm * Dc;
  const bf16_t* Bb = B + (size_t)bn * Dc;

  auto STAGE = [&](int buf, int k0) {
    bf16_t* Ad = As + buf * 8192;
    bf16_t* Bd = Bs + buf * 8192;
#pragma unroll
    for (int i = 0; i < 4; ++i)
      __builtin_amdgcn_global_load_lds(
          (const __attribute__((address_space(1))) void*)(Ab + (size_t)rS[i] * Dc + k0 + koS[i]),
          (__attribute__((address_space(3))) void*)(Ad + ((size_t)w * 64 + i * 256) * 8), 16, 0, 0);
#pragma unroll
    for (int i = 0; i < 4; ++i)
      __builtin_amdgcn_global_load_lds(
          (const __attribute__((address_space(1))) void*)(Bb + (size_t)rS[i] * Dc + k0 + koS[i]),
          (__attribute__((address_space(3))) void*)(Bd + ((size_t)w * 64 + i * 256) * 8), 16, 0, 0);
  };

  f32x4 acc[4][4] = {};
  STAGE(0, 0);
  __syncthreads();
  int cur = 0;
  for (int t = 0; t < 8; ++t) {
    if (t + 1 < 8) STAGE(cur ^ 1, (t + 1) << 6);
    const bf16_t* Ar = As + cur * 8192;
    const bf16_t* Br = Bs + cur * 8192;
    bf16x8 af[2][4], bf_[2][4];
#pragma unroll
    for (int h = 0; h < 2; ++h) {
#pragma unroll
      for (int m = 0; m < 4; ++m) {
        int row = wm + m * 16 + l15;
        af[h][m] = *(const bf16x8*)(Ar + swz_eoff(row, (h << 6) | (lhi << 4)));
        int col = wn + m * 16 + l15;
        bf_[h][m] = *(const bf16x8*)(Br + swz_eoff(col, (h << 6) | (lhi << 4)));
      }
    }
#pragma unroll
    for (int h = 0; h < 2; ++h)
#pragma unroll
      for (int m = 0; m < 4; ++m)
#pragma unroll
        for (int n = 0; n < 4; ++n)
          acc[m][n] = __builtin_amdgcn_mfma_f32_16x16x32_bf16(af[h][m], bf_[h][n], acc[m][n], 0, 0, 0);
    __syncthreads();
    cur ^= 1;
  }

  if (ntile == 3) {   // gates
#pragma unroll
    for (int m = 0; m < 4; ++m)
#pragma unroll
      for (int n = 0; n < 4; ++n)
#pragma unroll
        for (int q = 0; q < 4; ++q) {
          int c = wn + n * 16 + l15;
          if (c <= 1) {
            int row = bm + wm + m * 16 + lhi * 4 + q;
            float val = acc[m][n][q] + bias[384 + c];
            if (c == 0) gwb[row] = 1.f / (1.f + expf(-val));
            else gfb[row] = 0.9f / (1.f + expf(-val));
          }
        }
    return;
  }
  // acc -> fp32 tile (overlaps dead As/Bs; all threads are past the loop's final barrier)
#pragma unroll
  for (int m = 0; m < 4; ++m)
#pragma unroll
    for (int n = 0; n < 4; ++n)
#pragma unroll
      for (int q = 0; q < 4; ++q) {
        int row = wm + m * 16 + lhi * 4 + q;
        int col = wn + n * 16 + l15;
        float val = acc[m][n][q] + bias[ntile * 128 + col];
        if (ntile == 2) val = tanhf(val);
        tile[row * 129 + col] = val;
      }
  __syncthreads();

  const int b = bm >> 8;
  const int s0 = bm & 255;

  if (ntile <= 1) {
    int row = tid >> 1, off = (tid & 1) * 64;
    float ss = 0.f;
#pragma unroll
    for (int e = 0; e < 64; ++e) { float v = tile[row * 129 + off + e]; ss += v * v; }
    ss += __shfl_xor(ss, 1);
    if (!(tid & 1)) rno[row] = 1.f / fmaxf(sqrtf(ss), 1e-12f);
    __syncthreads();
    float rn = rno[row];
    bf16_t* dst = (ntile == 0 ? kb : qb) + (size_t)(bm + row) * Mc + off;
#pragma unroll
    for (int j = 0; j < 8; ++j) {
      bf16_t o[8];
#pragma unroll
      for (int e = 0; e < 8; ++e) o[e] = (bf16_t)(tile[row * 129 + off + j * 8 + e] * rn);
      *(bf16x8*)(dst + j * 8) = *(bf16x8*)o;
    }
  }
  if (ntile == 0 || ntile == 2) {
    int d = tid >> 1, s8 = (tid & 1) * 64;
    bf16_t* dst = (ntile == 0 ? kt : vt) + ((size_t)b * Mc + d) * Tc + s0 + s8;
#pragma unroll
    for (int j = 0; j < 8; ++j) {
      bf16_t o[8];
#pragma unroll
      for (int e = 0; e < 8; ++e) {
        int s = s8 + j * 8 + e;
        float v = tile[s * 129 + d];
        if (ntile == 0) v *= rno[s];
        o[e] = (bf16_t)v;
      }
      *(bf16x8*)(dst + j * 8) = *(bf16x8*)o;
    }
  }
}

DEV void attn_stage(char* smem, int tid, int role, int b,
                    const bf16_t* qb, const bf16_t* kb,
                    const bf16_t* vt, const bf16_t* kt,
                    const float* gwb, const float* gfb,
                    bf16_t* rd, float* states) {
  bf16_t* Ps = (bf16_t*)smem;
  float* sc = (float*)(smem + 65536);
  float* sgw = sc + Tc;
  float* sw = sgw + Tc;
  const int w = tid >> 6, l = tid & 63;
  const int wm = (w >> 1) * 64, wn = (w & 1) * 64;
  const int l15 = l & 15, lhi = l >> 4;

  sc[tid] = logf(gfb[b * Tc + tid]);
  sgw[tid] = gwb[b * Tc + tid];
  __syncthreads();
  for (int o = 1; o < Tc; o <<= 1) {
    float v = (tid >= o) ? sc[tid - o] : 0.f;
    __syncthreads();
    sc[tid] += v;
    __syncthreads();
  }
  sw[tid] = sgw[tid] * expf(sc[Tc - 1] - sc[tid]);
  __syncthreads();

  if (role == 2) {
    const bf16_t* Ab = vt + (size_t)b * Mc * Tc;
    const bf16_t* Bb = kt + (size_t)b * Mc * Tc;
    f32x4 acc[4][4] = {};
#pragma unroll
    for (int ks = 0; ks < 4; ++ks) {
#pragma unroll
      for (int h = 0; h < 2; ++h) {
        int ko = ks * 64 + h * 32 + lhi * 8;
        bf16x8 af[4], bf_[4];
#pragma unroll
        for (int m = 0; m < 4; ++m) {
          bf16x8 raw = *(const bf16x8*)(Ab + (size_t)(wm + m * 16 + l15) * Tc + ko);
          bf16_t sa[8];
#pragma unroll
          for (int e = 0; e < 8; ++e) sa[e] = (bf16_t)((float)raw[e] * sw[ko + e]);
          af[m] = *(bf16x8*)sa;
        }
#pragma unroll
        for (int n = 0; n < 4; ++n)
          bf_[n] = *(const bf16x8*)(Bb + (size_t)(wn + n * 16 + l15) * Tc + ko);
#pragma unroll
        for (int m = 0; m < 4; ++m)
#pragma unroll
          for (int n = 0; n < 4; ++n)
            acc[m][n] = __builtin_amdgcn_mfma_f32_16x16x32_bf16(af[m], bf_[n], acc[m][n], 0, 0, 0);
      }
    }
#pragma unroll
    for (int m = 0; m < 4; ++m)
#pragma unroll
      for (int n = 0; n < 4; ++n)
#pragma unroll
        for (int q = 0; q < 4; ++q) {
          int row = wm + m * 16 + lhi * 4 + q;
          int col = wn + n * 16 + l15;
          __builtin_nontemporal_store(acc[m][n][q], states + ((size_t)b * Mc + row) * Mc + col);
        }
    return;
  }

  const int q0 = role * 128;
  const bf16_t* Aq = qb + (size_t)(b * Tc + q0) * Mc;
#pragma unroll 1
  for (int nt2 = 0; nt2 < 2; ++nt2) {
    const bf16_t* Bk = kb + (size_t)(b * Tc + nt2 * 128) * Mc;
    f32x4 acc[4][4] = {};
#pragma unroll
    for (int kk = 0; kk < 2; ++kk) {
#pragma unroll
      for (int h = 0; h < 2; ++h) {
        int ko = kk * 64 + h * 32 + lhi * 8;
        bf16x8 af[4], bf_[4];
#pragma unroll
        for (int m = 0; m < 4; ++m)
          af[m] = *(const bf16x8*)(Aq + (size_t)(wm + m * 16 + l15) * Mc + ko);
#pragma unroll
        for (int n = 0; n < 4; ++n)
          bf_[n] = *(const bf16x8*)(Bk + (size_t)(wn + n * 16 + l15) * Mc + ko);
#pragma unroll
        for (int m = 0; m < 4; ++m)
#pragma unroll
          for (int n = 0; n < 4; ++n)
            acc[m][n] = __builtin_amdgcn_mfma_f32_16x16x32_bf16(af[m], bf_[n], acc[m][n], 0, 0, 0);
      }
    }
#pragma unroll
    for (int m = 0; m < 4; ++m)
#pragma unroll
      for (int n = 0; n < 4; ++n)
#pragma unroll
        for (int q = 0; q < 4; ++q) {
          int tr = wm + m * 16 + lhi * 4 + q;
          int scol = nt2 * 128 + wn + n * 16 + l15;
          int tg = q0 + tr;
          float val = acc[m][n][q];
          if (scol < tg)
            val *= sgw[scol] * expf(sc[tg - 1] - sc[scol]);
          else
            val = 0.f;
          int byte = (scol * 2) ^ ((tr & 7) << 4);
          Ps[tr * 256 + (byte >> 1)] = (bf16_t)val;
        }
  }
  __syncthreads();
  {
    const bf16_t* Bb = vt + (size_t)b * Mc * Tc;
    f32x4 acc[4][4] = {};
#pragma unroll
    for (int ks = 0; ks < 4; ++ks) {
#pragma unroll
      for (int h = 0; h < 2; ++h) {
        bf16x8 af[4], bf_[4];
#pragma unroll
        for (int m = 0; m < 4; ++m) {
          int row = wm + m * 16 + l15;
          int byteA = (ks * 128 + h * 64 + lhi * 16) ^ ((row & 7) << 4);
          af[m] = *(const bf16x8*)(Ps + row * 256 + (byteA >> 1));
        }
        int ko = ks * 64 + h * 32 + lhi * 8;
#pragma unroll
        for (int n = 0; n < 4; ++n)
          bf_[n] = *(const bf16x8*)(Bb + (size_t)(wn + n * 16 + l15) * Tc + ko);
#pragma unroll
        for (int m = 0; m < 4; ++m)
#pragma unroll
          for (int n = 0; n < 4; ++n)
            acc[m][n] = __builtin_amdgcn_mfma_f32_16x16x32_bf16(af[m], bf_[n], acc[m][n], 0, 0, 0);
      }
    }
#pragma unroll
    for (int m = 0; m < 4; ++m)
#pragma unroll
      for (int n = 0; n < 4; ++n)
#pragma unroll
        for (int q = 0; q < 4; ++q) {
          int row = wm + m * 16 + lhi * 4 + q;
          int col = wn + n * 16 + l15;
          rd[(size_t)(b * Tc + q0 + row) * Mc + col] = (bf16_t)acc[m][n][q];
        }
  }
}

template <bool HasPart>
DEV void lnrow_stage(int bid, int tid, const float* part, const float* bias,
                     float* x, const float* g, const float* b, bf16_t* xn) {
#pragma unroll
  for (int it = 0; it < 2; ++it) {
    int r = bid * 8 + it * 4 + (tid >> 6);
    int t = tid & 63;
    float xv[8];
    const float4* xr = (const float4*)(x + (size_t)r * Dc);
    if (HasPart) {
      const float4* p0 = (const float4*)(part + (size_t)r * Dc);
      const float4* p1 = (const float4*)(part + (size_t)(Rc + r) * Dc);
      const float4* bb4 = (const float4*)bias;
#pragma unroll
      for (int j = 0; j < 2; ++j) {
        float4 a = xr[2 * t + j], q = p0[2 * t + j], w2 = p1[2 * t + j], c = bb4[2 * t + j];
        xv[4 * j + 0] = a.x + q.x + w2.x + c.x;
        xv[4 * j + 1] = a.y + q.y + w2.y + c.y;
        xv[4 * j + 2] = a.z + q.z + w2.z + c.z;
        xv[4 * j + 3] = a.w + q.w + w2.w + c.w;
      }
      float4* xw = (float4*)(x + (size_t)r * Dc);
      xw[2 * t] = *(float4*)&xv[0];
      xw[2 * t + 1] = *(float4*)&xv[4];
    } else {
      *(float4*)&xv[0] = xr[2 * t];
      *(float4*)&xv[4] = xr[2 * t + 1];
    }
    float s = 0.f, ss = 0.f;
#pragma unroll
    for (int e = 0; e < 8; ++e) { s += xv[e]; ss += xv[e] * xv[e]; }
    s = wred64(s); ss = wred64(ss);
    float mu = s * (1.f / Dc);
    float inv = 1.f / sqrtf(ss * (1.f / Dc) - mu * mu + 1e-5f);
    float gg[8], bv[8];
    *(float4*)&gg[0] = ((const float4*)g)[2 * t];
    *(float4*)&gg[4] = ((const float4*)g)[2 * t + 1];
    *(float4*)&bv[0] = ((const float4*)b)[2 * t];
    *(float4*)&bv[4] = ((const float4*)b)[2 * t + 1];
    bf16_t ob[8];
#pragma unroll
    for (int e = 0; e < 8; ++e) ob[e] = (bf16_t)((xv[e] - mu) * inv * gg[e] + bv[e]);
    *(bf16x8*)(xn + (size_t)r * Dc + t * 8) = *(bf16x8*)ob;
  }
}

struct KArgs {
  const bf16_t *wkqv, *wo, *w1, *w2;
  const float *bkqv, *bo, *b1, *b2;
  const float *ln1g, *ln1b, *ln2g, *ln2b, *lnfg, *lnfb;
  float *x, *gwb, *gfb, *part, *states;
  bf16_t *xn, *kb, *qb, *kt, *vt, *rd, *h1;
};

__global__ __launch_bounds__(256, 1) void layers_k(KArgs a) {
  __shared__ alignas(16) char smem[68608];
  cg::grid_group grid = cg::this_grid();
  const int bid = blockIdx.x, tid = threadIdx.x;

  for (int ly = 0; ly < Lc; ++ly) {
    if (bid < 64)
      kqv_stage(smem, tid, bid & 3, bid >> 2,
                a.xn, a.wkqv + (size_t)ly * 512 * Dc, a.bkqv + ly * 512,
                a.kb, a.qb, a.kt, a.vt, a.gwb, a.gfb);
    grid.sync();
    if (bid < 24)
      attn_stage(smem, tid, bid % 3, bid / 3, a.qb, a.kb, a.vt, a.kt,
                 a.gwb, a.gfb, a.rd, a.states + (size_t)ly * Bc * Mc * Mc);
    grid.sync();
    if (bid < 64)
      mm_stage<A_NONE, true, false>(smem, tid, (bid >> 2) * 128, (bid & 3) * 128, 0,
                                    a.rd, a.wo + (size_t)ly * Dc * Mc, a.x, a.bo + ly * Dc,
                                    Mc, Mc, Mc, Dc, 0, 0, 0);
    grid.sync();
    lnrow_stage<false>(bid, tid, nullptr, nullptr, a.x,
                       a.ln2g + ly * Dc, a.ln2b + ly * Dc, a.xn);
    grid.sync();
    mm_stage<A_GELU, false, true>(smem, tid, (bid >> 4) * 128, (bid & 15) * 128, 0,
                                  a.xn, a.w1 + (size_t)ly * Hc * Dc, a.h1, a.b1 + ly * Hc,
                                  Dc, Dc, Dc, Hc, 0, 0, 0);
    grid.sync();
    if (bid < 128) {
      int z = bid >> 6, rem = bid & 63;
      mm_stage<A_NONE, false, false>(smem, tid, (rem >> 2) * 128, (rem & 3) * 128, z,
                                     a.h1, a.w2 + (size_t)ly * Dc * Hc, a.part, nullptr,
                                     Hc / 2, Hc, Hc, Dc, Hc / 2, Hc / 2, (long long)Rc * Dc);
    }
    grid.sync();
    {
      const float* ng = (ly < Lc - 1) ? a.ln1g + (size_t)(ly + 1) * Dc : a.lnfg;
      const float* nb = (ly < Lc - 1) ? a.ln1b + (size_t)(ly + 1) * Dc : a.lnfb;
      lnrow_stage<true>(bid, tid, a.part, a.b2 + ly * Dc, a.x, ng, nb, a.xn);
    }
    grid.sync();
  }
}

// ---------------------------------------------------------------- launcher
extern "C" void kernel_launch(void* const* d_in, const int* in_sizes, int n_in,
                              void* d_out, int out_size, void* d_ws, size_t ws_size,
                              hipStream_t stream) {
  const int* idx = (const int*)d_in[0];
  const float* center = (const float*)d_in[1];
  // d_in[2] offset: dead code (x = (b_min+b_max)/2 = center)
  const float* wk = (const float*)d_in[3];
  const float* bk = (const float*)d_in[4];
  const float* wq = (const float*)d_in[5];
  const float* bq = (const float*)d_in[6];
  const float* wv = (const float*)d_in[7];
  const float* bv = (const float*)d_in[8];
  const float* wo = (const float*)d_in[9];
  const float* bo = (const float*)d_in[10];
  const float* wgw = (const float*)d_in[11];
  const float* bgw = (const float*)d_in[12];
  const float* wgf = (const float*)d_in[13];
  const float* bgf = (const float*)d_in[14];
  const float* ln1_g = (const float*)d_in[15];
  const float* ln1_b = (const float*)d_in[16];
  const float* ln2_g = (const float*)d_in[17];
  const float* ln2_b = (const float*)d_in[18];
  const float* w1 = (const float*)d_in[19];
  const float* b1 = (const float*)d_in[20];
  const float* w2 = (const float*)d_in[21];
  const float* b2 = (const float*)d_in[22];
  const float* lnf_g = (const float*)d_in[23];
  const float* lnf_b = (const float*)d_in[24];
  const float* logit_scale = (const float*)d_in[25];

  float* logits = (float*)d_out;                     // [R, V] fp32
  float* states = logits + (size_t)Rc * Vc;          // [L, B, M, M] fp32

  char* p = (char*)d_ws;
  auto alloc = [&](size_t bytes) -> char* {
    char* r = p;
    p += (bytes + 255) & ~(size_t)255;
    return r;
  };
  float* x    = (float*)alloc((size_t)Rc * Dc * 4);
  float* gwb  = (float*)alloc(Rc * 4);
  float* gfb  = (float*)alloc(Rc * 4);
  float* bkqv = (float*)alloc(Lc * 512 * 4);
  float* part = (float*)alloc((size_t)2 * Rc * Dc * 4);
  bf16_t* xn_bf   = (bf16_t*)alloc((size_t)Rc * Dc * 2);
  bf16_t* h1_bf   = (bf16_t*)alloc((size_t)Rc * Hc * 2);
  bf16_t* k_bf    = (bf16_t*)alloc((size_t)Rc * Mc * 2);
  bf16_t* q_bf    = (bf16_t*)alloc((size_t)Rc * Mc * 2);
  bf16_t* rd_bf   = (bf16_t*)alloc((size_t)Rc * Mc * 2);
  bf16_t* kt_bf   = (bf16_t*)alloc((size_t)Bc * Mc * Tc * 2);
  bf16_t* vt_bf   = (bf16_t*)alloc((size_t)Bc * Mc * Tc * 2);
  bf16_t* cen_bf  = (bf16_t*)alloc((size_t)Vc * Dc * 2);
  bf16_t* w1_bf   = (bf16_t*)alloc((size_t)Lc * Hc * Dc * 2);
  bf16_t* w2_bf   = (bf16_t*)alloc((size_t)Lc * Dc * Hc * 2);
  bf16_t* wo_bf   = (bf16_t*)alloc((size_t)Lc * Dc * Mc * 2);
  bf16_t* wkqv_bf = (bf16_t*)alloc((size_t)Lc * 512 * Dc * 2);

  pre_k<<<13768, 256, 0, stream>>>(center, cen_bf, w1, w1_bf, w2, w2_bf, wo, wo_bf,
                                   wk, wq, wv, wgw, wgf, wkqv_bf,
                                   bk, bq, bv, bgw, bgf, bkqv,
                                   idx, ln1_g, ln1_b, x, xn_bf);

  KArgs ka;
  ka.wkqv = wkqv_bf; ka.wo = wo_bf; ka.w1 = w1_bf; ka.w2 = w2_bf;
  ka.bkqv = bkqv; ka.bo = bo; ka.b1 = b1; ka.b2 = b2;
  ka.ln1g = ln1_g; ka.ln1b = ln1_b; ka.ln2g = ln2_g; ka.ln2b = ln2_b;
  ka.lnfg = lnf_g; ka.lnfb = lnf_b;
  ka.x = x; ka.gwb = gwb; ka.gfb = gfb; ka.part = part; ka.states = states;
  ka.xn = xn_bf; ka.kb = k_bf; ka.qb = q_bf; ka.kt = kt_bf; ka.vt = vt_bf;
  ka.rd = rd_bf; ka.h1 = h1_bf;

  // Gated cooperative launch with checked error; fallback = proven round-7 sequence.
  bool did_coop = false;
  int dev = 0;
  (void)hipGetDevice(&dev);
  int coop = 0;
  (void)hipDeviceGetAttribute(&coop, hipDeviceAttributeCooperativeLaunch, dev);
  if (coop) {
    void* kparams[] = {(void*)&ka};
    hipError_t err = hipLaunchCooperativeKernel((void*)layers_k, dim3(256), dim3(256),
                                                kparams, 0, stream);
    did_coop = (err == hipSuccess);
  }

  const long long zero = 0;
  if (!did_coop) {
    for (int l = 0; l < Lc; ++l) {
      kqvprep_k<<<dim3(4, 16), 256, 0, stream>>>(
          xn_bf, wkqv_bf + (size_t)l * 512 * Dc, bkqv + l * 512,
          k_bf, q_bf, kt_bf, vt_bf, gwb, gfb);

      attn_k<<<dim3(3, Bc), 256, 0, stream>>>(q_bf, k_bf, vt_bf, kt_bf, gwb, gfb,
                                              rd_bf, states + (size_t)l * Bc * Mc * Mc);

      mms_k<A_NONE, true, false><<<dim3(4, 16, 1), 256, 0, stream>>>(
          rd_bf, wo_bf + (size_t)l * Dc * Mc, x, bo + (size_t)l * Dc,
          Mc, Mc, Mc, Dc, zero, zero, zero);

      ln_k<<<Rc, 64, 0, stream>>>(x, ln2_g + (size_t)l * Dc, ln2_b + (size_t)l * Dc, xn_bf);

      mms_k<A_GELU, false, true><<<dim3(16, 16, 1), 256, 0, stream>>>(
          xn_bf, w1_bf + (size_t)l * Hc * Dc, h1_bf, b1 + (size_t)l * Hc,
          Dc, Dc, Dc, Hc, zero, zero, zero);

      mms_k<A_NONE, false, false><<<dim3(4, 16, 2), 256, 0, stream>>>(
          h1_bf, w2_bf + (size_t)l * Dc * Hc, part, nullptr,
          Hc / 2, Hc, Hc, Dc, (long long)(Hc / 2), (long long)(Hc / 2), (long long)Rc * Dc);

      const float* ng = (l < Lc - 1) ? ln1_g + (size_t)(l + 1) * Dc : lnf_g;
      const float* nb = (l < Lc - 1) ? ln1_b + (size_t)(l + 1) * Dc : lnf_b;
      redln_k<<<Rc, 64, 0, stream>>>(part, b2 + (size_t)l * Dc, x, ng, nb, xn_bf);
    }
  }

  mm_k<A_NONE, false, true, false, true><<<dim3(250, 16, 1), 256, 0, stream>>>(
      xn_bf, cen_bf, logits, nullptr, Dc, Dc, Dc, Vc, zero, zero, zero,
      logit_scale, 0.044194173824159223f);
}

// Round 12
// 629.329 us; speedup vs baseline: 2.5096x; 2.5096x over previous
//
#include <hip/hip_runtime.h>
#include <math.h>

// Problem constants
constexpr int Bc = 8, Tc = 256, Dc = 512, Mc = 128, Lc = 4, Vc = 32000;
constexpr int Rc = Bc * Tc;          // 2048 rows
constexpr int Hc = 4 * Dc;           // 2048 hidden

typedef __bf16 bf16_t;
typedef __bf16 bf16x8 __attribute__((ext_vector_type(8)));
typedef float f32x4 __attribute__((ext_vector_type(4)));
static_assert(sizeof(bf16x8) == 16, "bf16x8 must be 16B");

#define DEV __device__ __forceinline__

DEV float wred64(float x) {
#pragma unroll
  for (int o = 32; o; o >>= 1) x += __shfl_xor(x, o);
  return x;
}

// ---------------------------------------------------------------- merged preamble:
// blocks [0,12224): fp32->bf16 cvt (center 8000 | w1 2048 | w2 2048 | wo 128; 2048 elems/blk)
// blocks [12224,13248): pack wkqv rows (2 rows/blk)
// blocks [13248,13256): pack bkqv
// blocks [13256,13768): gather + ln1(layer0) (4 rows/blk, one per wave)
__global__ __launch_bounds__(256) void pre_k(
    const float* __restrict__ center, bf16_t* __restrict__ cen_bf,
    const float* __restrict__ w1, bf16_t* __restrict__ w1_bf,
    const float* __restrict__ w2, bf16_t* __restrict__ w2_bf,
    const float* __restrict__ wo, bf16_t* __restrict__ wo_bf,
    const float* __restrict__ wk, const float* __restrict__ wq,
    const float* __restrict__ wv, const float* __restrict__ wgw,
    const float* __restrict__ wgf, bf16_t* __restrict__ wkqv_bf,
    const float* __restrict__ bk, const float* __restrict__ bq,
    const float* __restrict__ bv, const float* __restrict__ bgw,
    const float* __restrict__ bgf, float* __restrict__ bkqv,
    const int* __restrict__ idx, const float* __restrict__ g1,
    const float* __restrict__ b1, float* __restrict__ x,
    bf16_t* __restrict__ xn) {
  int blk = blockIdx.x, t = threadIdx.x;
  if (blk < 12224) {
    const float* src; bf16_t* dst; int base;
    if (blk < 8000)       { src = center; dst = cen_bf; base = blk; }
    else if (blk < 10048) { src = w1; dst = w1_bf; base = blk - 8000; }
    else if (blk < 12096) { src = w2; dst = w2_bf; base = blk - 10048; }
    else                  { src = wo; dst = wo_bf; base = blk - 12096; }
    size_t i = (size_t)base * 2048 + (size_t)t * 8;
    float4 a = *(const float4*)(src + i);
    float4 b = *(const float4*)(src + i + 4);
    bf16_t o[8] = {(bf16_t)a.x, (bf16_t)a.y, (bf16_t)a.z, (bf16_t)a.w,
                   (bf16_t)b.x, (bf16_t)b.y, (bf16_t)b.z, (bf16_t)b.w};
    *(bf16x8*)(dst + i) = *(bf16x8*)o;
  } else if (blk < 13248) {
    int row = (blk - 12224) * 2 + (t >> 7);
    int t7 = t & 127;
    int lyr = row >> 9, o = row & 511;
    const float* src = nullptr;
    if (o < 128) src = wk + ((size_t)lyr * 128 + o) * Dc;
    else if (o < 256) src = wq + ((size_t)lyr * 128 + (o - 128)) * Dc;
    else if (o < 384) src = wv + ((size_t)lyr * 128 + (o - 256)) * Dc;
    else if (o == 384) src = wgw + (size_t)lyr * Dc;
    else if (o == 385) src = wgf + (size_t)lyr * Dc;
    bf16_t* dst = wkqv_bf + (size_t)row * Dc + t7 * 4;
    if (src) {
      float4 v = ((const float4*)src)[t7];
      dst[0] = (bf16_t)v.x; dst[1] = (bf16_t)v.y; dst[2] = (bf16_t)v.z; dst[3] = (bf16_t)v.w;
    } else {
      dst[0] = dst[1] = dst[2] = dst[3] = (bf16_t)0.f;
    }
  } else if (blk < 13256) {
    int i = (blk - 13248) * 256 + t;
    int lyr = i >> 9, o = i & 511;
    float v = 0.f;
    if (o < 128) v = bk[lyr * 128 + o];
    else if (o < 256) v = bq[lyr * 128 + o - 128];
    else if (o < 384) v = bv[lyr * 128 + o - 256];
    else if (o == 384) v = bgw[lyr];
    else if (o == 385) v = bgf[lyr];
    bkqv[i] = v;
  } else {
    int r = (blk - 13256) * 4 + (t >> 6);
    int t6 = t & 63;
    const float4* row = (const float4*)(center + (size_t)idx[r] * Dc);
    float xv[8];
    *(float4*)&xv[0] = row[2 * t6];
    *(float4*)&xv[4] = row[2 * t6 + 1];
    float4* xrow = (float4*)(x + (size_t)r * Dc);
    xrow[2 * t6] = *(float4*)&xv[0];
    xrow[2 * t6 + 1] = *(float4*)&xv[4];
    float s = 0.f, ss = 0.f;
#pragma unroll
    for (int e = 0; e < 8; ++e) { s += xv[e]; ss += xv[e] * xv[e]; }
    s = wred64(s); ss = wred64(ss);
    float mu = s * (1.f / Dc);
    float inv = 1.f / sqrtf(ss * (1.f / Dc) - mu * mu + 1e-5f);
    float gg[8], bb[8];
    *(float4*)&gg[0] = ((const float4*)g1)[2 * t6];
    *(float4*)&gg[4] = ((const float4*)g1)[2 * t6 + 1];
    *(float4*)&bb[0] = ((const float4*)b1)[2 * t6];
    *(float4*)&bb[4] = ((const float4*)b1)[2 * t6 + 1];
    bf16_t ob[8];
#pragma unroll
    for (int e = 0; e < 8; ++e) ob[e] = (bf16_t)((xv[e] - mu) * inv * gg[e] + bb[e]);
    *(bf16x8*)(xn + (size_t)r * Dc + t6 * 8) = *(bf16x8*)ob;
  }
}

// ---------------------------------------------------------------- LayerNorm -> bf16 (ln2)
__global__ __launch_bounds__(64) void ln_k(const float* __restrict__ in,
                                           const float* __restrict__ g,
                                           const float* __restrict__ b,
                                           bf16_t* __restrict__ out) {
  int r = blockIdx.x, t = threadIdx.x;
  const float4* row = (const float4*)(in + (size_t)r * Dc);
  float xv[8];
  *(float4*)&xv[0] = row[2 * t];
  *(float4*)&xv[4] = row[2 * t + 1];
  float s = 0.f, ss = 0.f;
#pragma unroll
  for (int e = 0; e < 8; ++e) { s += xv[e]; ss += xv[e] * xv[e]; }
  s = wred64(s); ss = wred64(ss);
  float mu = s * (1.f / Dc);
  float inv = 1.f / sqrtf(ss * (1.f / Dc) - mu * mu + 1e-5f);
  float gg[8], bb[8];
  *(float4*)&gg[0] = ((const float4*)g)[2 * t];
  *(float4*)&gg[4] = ((const float4*)g)[2 * t + 1];
  *(float4*)&bb[0] = ((const float4*)b)[2 * t];
  *(float4*)&bb[4] = ((const float4*)b)[2 * t + 1];
  bf16_t ob[8];
#pragma unroll
  for (int e = 0; e < 8; ++e) ob[e] = (bf16_t)((xv[e] - mu) * inv * gg[e] + bb[e]);
  *(bf16x8*)(out + (size_t)r * Dc + t * 8) = *(bf16x8*)ob;
}

// ---------------------------------------------------------------- split-K reduce + bias + residual + LN
__global__ __launch_bounds__(64) void redln_k(const float* __restrict__ part,
                                              const float* __restrict__ bias,
                                              float* __restrict__ x,
                                              const float* __restrict__ g,
                                              const float* __restrict__ b,
                                              bf16_t* __restrict__ xn) {
  int r = blockIdx.x, t = threadIdx.x;
  const float4* xr = (const float4*)(x + (size_t)r * Dc);
  const float4* p0 = (const float4*)(part + (size_t)r * Dc);
  const float4* p1 = (const float4*)(part + (size_t)(Rc + r) * Dc);
  const float4* bb4 = (const float4*)bias;
  float xv[8];
#pragma unroll
  for (int j = 0; j < 2; ++j) {
    float4 a = xr[2 * t + j], q = p0[2 * t + j], w = p1[2 * t + j], c = bb4[2 * t + j];
    xv[4 * j + 0] = a.x + q.x + w.x + c.x;
    xv[4 * j + 1] = a.y + q.y + w.y + c.y;
    xv[4 * j + 2] = a.z + q.z + w.z + c.z;
    xv[4 * j + 3] = a.w + q.w + w.w + c.w;
  }
  float4* xw = (float4*)(x + (size_t)r * Dc);
  xw[2 * t] = *(float4*)&xv[0];
  xw[2 * t + 1] = *(float4*)&xv[4];
  float s = 0.f, ss = 0.f;
#pragma unroll
  for (int e = 0; e < 8; ++e) { s += xv[e]; ss += xv[e] * xv[e]; }
  s = wred64(s); ss = wred64(ss);
  float mu = s * (1.f / Dc);
  float inv = 1.f / sqrtf(ss * (1.f / Dc) - mu * mu + 1e-5f);
  float gg[8], bv[8];
  *(float4*)&gg[0] = ((const float4*)g)[2 * t];
  *(float4*)&gg[4] = ((const float4*)g)[2 * t + 1];
  *(float4*)&bv[0] = ((const float4*)b)[2 * t];
  *(float4*)&bv[4] = ((const float4*)b)[2 * t + 1];
  bf16_t ob[8];
#pragma unroll
  for (int e = 0; e < 8; ++e) ob[e] = (bf16_t)((xv[e] - mu) * inv * gg[e] + bv[e]);
  *(bf16x8*)(xn + (size_t)r * Dc + t * 8) = *(bf16x8*)ob;
}

// ---------------------------------------------------------------- MFMA helpers
DEV int swz_eoff(int row, int kbyte) {
  return row * 64 + ((kbyte ^ ((row & 7) << 4)) >> 1);
}

enum { A_NONE = 0, A_GELU = 2 };

// shared epilogue (plain GEMMs)
template <int ACT, bool ACCUM, bool SCALE, bool OBF16>
DEV void mm_epi(f32x4 (&acc)[4][4], int bm, int bn, int wm, int wn, int lhi, int l15,
                void* Cv, const float* bias, int ldc, long long sC, int z, float sc) {
  float* Cf = (float*)Cv;
  bf16_t* Cb = (bf16_t*)Cv;
#pragma unroll
  for (int m = 0; m < 4; ++m) {
#pragma unroll
    for (int n = 0; n < 4; ++n) {
#pragma unroll
      for (int q = 0; q < 4; ++q) {
        int row = bm + wm + m * 16 + lhi * 4 + q;   // C/D: col=lane&15, row=(lane>>4)*4+reg (m89)
        int col = bn + wn + n * 16 + l15;
        float val = acc[m][n][q];
        if (bias) val += bias[col];
        if (ACT == A_GELU) {
          val = 0.5f * val * (1.f + erff(val * 0.70710678118654752f));
        }
        if (SCALE) val *= sc;
        size_t off = (size_t)z * sC + (size_t)row * ldc + col;
        if (OBF16) {
          Cb[off] = (bf16_t)val;
        } else if (SCALE) {
          __builtin_nontemporal_store(val, Cf + off);   // logits: write-once
        } else {
          if (ACCUM) val += Cf[off];
          Cf[off] = val;
        }
      }
    }
  }
}

// ---------------------------------------------------------------- logits GEMM: single-buffer, 3 blk/CU
template <int ACT, bool ACCUM, bool SCALE, bool OBF16, bool SWZ>
__global__ __launch_bounds__(256, 3) void mm_k(
    const bf16_t* __restrict__ A, const bf16_t* __restrict__ B, void* __restrict__ Cv,
    const float* __restrict__ bias, int K, int lda, int ldb, int ldc,
    long long sA, long long sB, long long sC,
    const float* __restrict__ scale_ptr, float scale_const) {
  __shared__ bf16_t As[128 * 64];
  __shared__ bf16_t Bs[128 * 64];
  const int z = blockIdx.z;
  int ntile, mtile;
  if (SWZ) {
    int nwg = gridDim.x * gridDim.y;           // logits: 4000, %8==0
    int orig = blockIdx.y * gridDim.x + blockIdx.x;
    int q = nwg >> 3;
    int id = (orig & 7) * q + (orig >> 3);     // bijective XCD chunking
    mtile = id % gridDim.y;
    ntile = id / gridDim.y;
  } else {
    ntile = blockIdx.x;
    mtile = blockIdx.y;
  }
  const int bm = mtile * 128, bn = ntile * 128;
  A += (size_t)z * sA;
  B += (size_t)z * sB;
  const int tid = threadIdx.x, w = tid >> 6, l = tid & 63;
  const int wm = (w >> 1) * 64, wn = (w & 1) * 64;
  const int l15 = l & 15, lhi = l >> 4;

  int rS[4], koS[4];
#pragma unroll
  for (int i = 0; i < 4; ++i) {
    int c = tid + i * 256;
    int r = c >> 3, kb = (c & 7) << 4;
    rS[i] = r;
    koS[i] = (kb ^ ((r & 7) << 4)) >> 1;
  }
  const bf16_t* Ab = A + (size_t)bm * lda;
  const bf16_t* Bb = B + (size_t)bn * ldb;

  f32x4 acc[4][4] = {};
  for (int k0 = 0; k0 < K; k0 += 64) {
#pragma unroll
    for (int i = 0; i < 4; ++i) {
      __builtin_amdgcn_global_load_lds(
          (const __attribute__((address_space(1))) void*)(Ab + (size_t)rS[i] * lda + k0 + koS[i]),
          (__attribute__((address_space(3))) void*)(As + ((size_t)w * 64 + i * 256) * 8), 16, 0, 0);
    }
#pragma unroll
    for (int i = 0; i < 4; ++i) {
      __builtin_amdgcn_global_load_lds(
          (const __attribute__((address_space(1))) void*)(Bb + (size_t)rS[i] * ldb + k0 + koS[i]),
          (__attribute__((address_space(3))) void*)(Bs + ((size_t)w * 64 + i * 256) * 8), 16, 0, 0);
    }
    __syncthreads();
    bf16x8 af[2][4], bf_[2][4];
#pragma unroll
    for (int h = 0; h < 2; ++h) {
#pragma unroll
      for (int m = 0; m < 4; ++m) {
        int row = wm + m * 16 + l15;
        af[h][m] = *(const bf16x8*)(As + swz_eoff(row, (h << 6) | (lhi << 4)));
        int col = wn + m * 16 + l15;
        bf_[h][m] = *(const bf16x8*)(Bs + swz_eoff(col, (h << 6) | (lhi << 4)));
      }
    }
#pragma unroll
    for (int h = 0; h < 2; ++h)
#pragma unroll
      for (int m = 0; m < 4; ++m)
#pragma unroll
        for (int n = 0; n < 4; ++n)
          acc[m][n] = __builtin_amdgcn_mfma_f32_16x16x32_bf16(af[h][m], bf_[h][n], acc[m][n], 0, 0, 0);
    __syncthreads();
  }
  float sc = SCALE ? scale_const * scale_ptr[0] : 1.f;
  mm_epi<ACT, ACCUM, SCALE, OBF16>(acc, bm, bn, wm, wn, lhi, l15, Cv, bias, ldc, sC, z, sc);
}

// ---------------------------------------------------------------- small GEMM: 2-phase dbuf
template <int ACT, bool ACCUM, bool OBF16>
__global__ __launch_bounds__(256, 2) void mms_k(
    const bf16_t* __restrict__ A, const bf16_t* __restrict__ B, void* __restrict__ Cv,
    const float* __restrict__ bias, int K, int lda, int ldb, int ldc,
    long long sA, long long sB, long long sC) {
  __shared__ bf16_t As[2 * 128 * 64];
  __shared__ bf16_t Bs[2 * 128 * 64];
  const int z = blockIdx.z;
  const int bm = blockIdx.y * 128, bn = blockIdx.x * 128;
  A += (size_t)z * sA;
  B += (size_t)z * sB;
  const int tid = threadIdx.x, w = tid >> 6, l = tid & 63;
  const int wm = (w >> 1) * 64, wn = (w & 1) * 64;
  const int l15 = l & 15, lhi = l >> 4;

  int rS[4], koS[4];
#pragma unroll
  for (int i = 0; i < 4; ++i) {
    int c = tid + i * 256;
    int r = c >> 3, kb = (c & 7) << 4;
    rS[i] = r;
    koS[i] = (kb ^ ((r & 7) << 4)) >> 1;
  }
  const bf16_t* Ab = A + (size_t)bm * lda;
  const bf16_t* Bb = B + (size_t)bn * ldb;

  auto STAGE = [&](int buf, int k0) {
    bf16_t* Ad = As + buf * 8192;
    bf16_t* Bd = Bs + buf * 8192;
#pragma unroll
    for (int i = 0; i < 4; ++i)
      __builtin_amdgcn_global_load_lds(
          (const __attribute__((address_space(1))) void*)(Ab + (size_t)rS[i] * lda + k0 + koS[i]),
          (__attribute__((address_space(3))) void*)(Ad + ((size_t)w * 64 + i * 256) * 8), 16, 0, 0);
#pragma unroll
    for (int i = 0; i < 4; ++i)
      __builtin_amdgcn_global_load_lds(
          (const __attribute__((address_space(1))) void*)(Bb + (size_t)rS[i] * ldb + k0 + koS[i]),
          (__attribute__((address_space(3))) void*)(Bd + ((size_t)w * 64 + i * 256) * 8), 16, 0, 0);
  };

  f32x4 acc[4][4] = {};
  const int nt = K >> 6;
  STAGE(0, 0);
  __syncthreads();
  int cur = 0;
  for (int t = 0; t < nt; ++t) {
    if (t + 1 < nt) STAGE(cur ^ 1, (t + 1) << 6);
    const bf16_t* Ar = As + cur * 8192;
    const bf16_t* Br = Bs + cur * 8192;
    bf16x8 af[2][4], bf_[2][4];
#pragma unroll
    for (int h = 0; h < 2; ++h) {
#pragma unroll
      for (int m = 0; m < 4; ++m) {
        int row = wm + m * 16 + l15;
        af[h][m] = *(const bf16x8*)(Ar + swz_eoff(row, (h << 6) | (lhi << 4)));
        int col = wn + m * 16 + l15;
        bf_[h][m] = *(const bf16x8*)(Br + swz_eoff(col, (h << 6) | (lhi << 4)));
      }
    }
#pragma unroll
    for (int h = 0; h < 2; ++h)
#pragma unroll
      for (int m = 0; m < 4; ++m)
#pragma unroll
        for (int n = 0; n < 4; ++n)
          acc[m][n] = __builtin_amdgcn_mfma_f32_16x16x32_bf16(af[h][m], bf_[h][n], acc[m][n], 0, 0, 0);
    __syncthreads();
    cur ^= 1;
  }
  mm_epi<ACT, ACCUM, false, OBF16>(acc, bm, bn, wm, wn, lhi, l15, Cv, bias, ldc, sC, z, 1.f);
}

// ---------------------------------------------------------------- kqv GEMM + fused prep epilogue
// grid (4,16): ntile 0=k,1=q,2=v,3=gates; mtile over 2048 rows (128 each).
__global__ __launch_bounds__(256) void kqvprep_k(
    const bf16_t* __restrict__ A, const bf16_t* __restrict__ B,
    const float* __restrict__ bias,
    bf16_t* __restrict__ kb, bf16_t* __restrict__ qb,
    bf16_t* __restrict__ kt, bf16_t* __restrict__ vt,
    float* __restrict__ gwb, float* __restrict__ gfb) {
  __shared__ bf16_t As[2 * 128 * 64];
  __shared__ bf16_t Bs[2 * 128 * 64];
  __shared__ float tile[128 * 129];
  __shared__ float rno[128];
  const int ntile = blockIdx.x, mtile = blockIdx.y;
  const int bm = mtile * 128, bn = ntile * 128;
  const int tid = threadIdx.x, w = tid >> 6, l = tid & 63;
  const int wm = (w >> 1) * 64, wn = (w & 1) * 64;
  const int l15 = l & 15, lhi = l >> 4;

  int rS[4], koS[4];
#pragma unroll
  for (int i = 0; i < 4; ++i) {
    int c = tid + i * 256;
    int r = c >> 3, kbb = (c & 7) << 4;
    rS[i] = r;
    koS[i] = (kbb ^ ((r & 7) << 4)) >> 1;
  }
  const bf16_t* Ab = A + (size_t)bm * Dc;
  const bf16_t* Bb = B + (size_t)bn * Dc;

  auto STAGE = [&](int buf, int k0) {
    bf16_t* Ad = As + buf * 8192;
    bf16_t* Bd = Bs + buf * 8192;
#pragma unroll
    for (int i = 0; i < 4; ++i)
      __builtin_amdgcn_global_load_lds(
          (const __attribute__((address_space(1))) void*)(Ab + (size_t)rS[i] * Dc + k0 + koS[i]),
          (__attribute__((address_space(3))) void*)(Ad + ((size_t)w * 64 + i * 256) * 8), 16, 0, 0);
#pragma unroll
    for (int i = 0; i < 4; ++i)
      __builtin_amdgcn_global_load_lds(
          (const __attribute__((address_space(1))) void*)(Bb + (size_t)rS[i] * Dc + k0 + koS[i]),
          (__attribute__((address_space(3))) void*)(Bd + ((size_t)w * 64 + i * 256) * 8), 16, 0, 0);
  };

  f32x4 acc[4][4] = {};
  STAGE(0, 0);
  __syncthreads();
  int cur = 0;
  for (int t = 0; t < 8; ++t) {
    if (t + 1 < 8) STAGE(cur ^ 1, (t + 1) << 6);
    const bf16_t* Ar = As + cur * 8192;
    const bf16_t* Br = Bs + cur * 8192;
    bf16x8 af[2][4], bf_[2][4];
#pragma unroll
    for (int h = 0; h < 2; ++h) {
#pragma unroll
      for (int m = 0; m < 4; ++m) {
        int row = wm + m * 16 + l15;
        af[h][m] = *(const bf16x8*)(Ar + swz_eoff(row, (h << 6) | (lhi << 4)));
        int col = wn + m * 16 + l15;
        bf_[h][m] = *(const bf16x8*)(Br + swz_eoff(col, (h << 6) | (lhi << 4)));
      }
    }
#pragma unroll
    for (int h = 0; h < 2; ++h)
#pragma unroll
      for (int m = 0; m < 4; ++m)
#pragma unroll
        for (int n = 0; n < 4; ++n)
          acc[m][n] = __builtin_amdgcn_mfma_f32_16x16x32_bf16(af[h][m], bf_[h][n], acc[m][n], 0, 0, 0);
    __syncthreads();
    cur ^= 1;
  }

  if (ntile == 3) {   // gates
#pragma unroll
    for (int m = 0; m < 4; ++m)
#pragma unroll
      for (int n = 0; n < 4; ++n)
#pragma unroll
        for (int q = 0; q < 4; ++q) {
          int c = wn + n * 16 + l15;
          if (c <= 1) {
            int row = bm + wm + m * 16 + lhi * 4 + q;
            float val = acc[m][n][q] + bias[384 + c];
            if (c == 0) gwb[row] = 1.f / (1.f + expf(-val));
            else gfb[row] = 0.9f / (1.f + expf(-val));
          }
        }
    return;
  }
#pragma unroll
  for (int m = 0; m < 4; ++m)
#pragma unroll
    for (int n = 0; n < 4; ++n)
#pragma unroll
      for (int q = 0; q < 4; ++q) {
        int row = wm + m * 16 + lhi * 4 + q;
        int col = wn + n * 16 + l15;
        float val = acc[m][n][q] + bias[ntile * 128 + col];
        if (ntile == 2) val = tanhf(val);
        tile[row * 129 + col] = val;
      }
  __syncthreads();

  const int b = bm >> 8;
  const int s0 = bm & 255;

  if (ntile <= 1) {
    int row = tid >> 1, off = (tid & 1) * 64;
    float ss = 0.f;
#pragma unroll
    for (int e = 0; e < 64; ++e) { float v = tile[row * 129 + off + e]; ss += v * v; }
    ss += __shfl_xor(ss, 1);
    if (!(tid & 1)) rno[row] = 1.f / fmaxf(sqrtf(ss), 1e-12f);
    __syncthreads();
    float rn = rno[row];
    bf16_t* dst = (ntile == 0 ? kb : qb) + (size_t)(bm + row) * Mc + off;
#pragma unroll
    for (int j = 0; j < 8; ++j) {
      bf16_t o[8];
#pragma unroll
      for (int e = 0; e < 8; ++e) o[e] = (bf16_t)(tile[row * 129 + off + j * 8 + e] * rn);
      *(bf16x8*)(dst + j * 8) = *(bf16x8*)o;
    }
  }
  if (ntile == 0 || ntile == 2) {
    int d = tid >> 1, s8 = (tid & 1) * 64;
    bf16_t* dst = (ntile == 0 ? kt : vt) + ((size_t)b * Mc + d) * Tc + s0 + s8;
#pragma unroll
    for (int j = 0; j < 8; ++j) {
      bf16_t o[8];
#pragma unroll
      for (int e = 0; e < 8; ++e) {
        int s = s8 + j * 8 + e;
        float v = tile[s * 129 + d];
        if (ntile == 0) v *= rno[s];
        o[e] = (bf16_t)v;
      }
      *(bf16x8*)(dst + j * 8) = *(bf16x8*)o;
    }
  }
}

// ---------------------------------------------------------------- fused attention (in-kernel decay scan)
// grid (3, B): role 0/1 = q-tile -> rd; role 2 = states = (wgt*v)@kt^T
__global__ __launch_bounds__(256) void attn_k(
    const bf16_t* __restrict__ qb, const bf16_t* __restrict__ kb,
    const bf16_t* __restrict__ vt, const bf16_t* __restrict__ kt,
    const float* __restrict__ gwb, const float* __restrict__ gfb,
    bf16_t* __restrict__ rd, float* __restrict__ states) {
  __shared__ bf16_t Ps[128 * 256];
  __shared__ float sc[Tc], sgw[Tc], sw[Tc];
  const int role = blockIdx.x, b = blockIdx.y;
  const int tid = threadIdx.x, w = tid >> 6, l = tid & 63;
  const int wm = (w >> 1) * 64, wn = (w & 1) * 64;
  const int l15 = l & 15, lhi = l >> 4;

  sc[tid] = logf(gfb[b * Tc + tid]);
  sgw[tid] = gwb[b * Tc + tid];
  __syncthreads();
  for (int o = 1; o < Tc; o <<= 1) {
    float v = (tid >= o) ? sc[tid - o] : 0.f;
    __syncthreads();
    sc[tid] += v;
    __syncthreads();
  }
  sw[tid] = sgw[tid] * expf(sc[Tc - 1] - sc[tid]);
  __syncthreads();

  if (role == 2) {
    const bf16_t* Ab = vt + (size_t)b * Mc * Tc;
    const bf16_t* Bb = kt + (size_t)b * Mc * Tc;
    f32x4 acc[4][4] = {};
#pragma unroll
    for (int ks = 0; ks < 4; ++ks) {
#pragma unroll
      for (int h = 0; h < 2; ++h) {
        int ko = ks * 64 + h * 32 + lhi * 8;
        bf16x8 af[4], bf_[4];
#pragma unroll
        for (int m = 0; m < 4; ++m) {
          bf16x8 raw = *(const bf16x8*)(Ab + (size_t)(wm + m * 16 + l15) * Tc + ko);
          bf16_t sa[8];
#pragma unroll
          for (int e = 0; e < 8; ++e) sa[e] = (bf16_t)((float)raw[e] * sw[ko + e]);
          af[m] = *(bf16x8*)sa;
        }
#pragma unroll
        for (int n = 0; n < 4; ++n)
          bf_[n] = *(const bf16x8*)(Bb + (size_t)(wn + n * 16 + l15) * Tc + ko);
#pragma unroll
        for (int m = 0; m < 4; ++m)
#pragma unroll
          for (int n = 0; n < 4; ++n)
            acc[m][n] = __builtin_amdgcn_mfma_f32_16x16x32_bf16(af[m], bf_[n], acc[m][n], 0, 0, 0);
      }
    }
#pragma unroll
    for (int m = 0; m < 4; ++m)
#pragma unroll
      for (int n = 0; n < 4; ++n)
#pragma unroll
        for (int q = 0; q < 4; ++q) {
          int row = wm + m * 16 + lhi * 4 + q;
          int col = wn + n * 16 + l15;
          __builtin_nontemporal_store(acc[m][n][q], states + ((size_t)b * Mc + row) * Mc + col);
        }
    return;
  }

  const int q0 = role * 128;
  const bf16_t* Aq = qb + (size_t)(b * Tc + q0) * Mc;
#pragma unroll 1
  for (int nt2 = 0; nt2 < 2; ++nt2) {
    const bf16_t* Bk = kb + (size_t)(b * Tc + nt2 * 128) * Mc;
    f32x4 acc[4][4] = {};
#pragma unroll
    for (int kk = 0; kk < 2; ++kk) {
#pragma unroll
      for (int h = 0; h < 2; ++h) {
        int ko = kk * 64 + h * 32 + lhi * 8;
        bf16x8 af[4], bf_[4];
#pragma unroll
        for (int m = 0; m < 4; ++m)
          af[m] = *(const bf16x8*)(Aq + (size_t)(wm + m * 16 + l15) * Mc + ko);
#pragma unroll
        for (int n = 0; n < 4; ++n)
          bf_[n] = *(const bf16x8*)(Bk + (size_t)(wn + n * 16 + l15) * Mc + ko);
#pragma unroll
        for (int m = 0; m < 4; ++m)
#pragma unroll
          for (int n = 0; n < 4; ++n)
            acc[m][n] = __builtin_amdgcn_mfma_f32_16x16x32_bf16(af[m], bf_[n], acc[m][n], 0, 0, 0);
      }
    }
#pragma unroll
    for (int m = 0; m < 4; ++m)
#pragma unroll
      for (int n = 0; n < 4; ++n)
#pragma unroll
        for (int q = 0; q < 4; ++q) {
          int tr = wm + m * 16 + lhi * 4 + q;
          int scol = nt2 * 128 + wn + n * 16 + l15;
          int tg = q0 + tr;
          float val = acc[m][n][q];
          if (scol < tg)
            val *= sgw[scol] * expf(sc[tg - 1] - sc[scol]);
          else
            val = 0.f;
          int byte = (scol * 2) ^ ((tr & 7) << 4);
          Ps[tr * 256 + (byte >> 1)] = (bf16_t)val;
        }
  }
  __syncthreads();
  {
    const bf16_t* Bb = vt + (size_t)b * Mc * Tc;
    f32x4 acc[4][4] = {};
#pragma unroll
    for (int ks = 0; ks < 4; ++ks) {
#pragma unroll
      for (int h = 0; h < 2; ++h) {
        bf16x8 af[4], bf_[4];
#pragma unroll
        for (int m = 0; m < 4; ++m) {
          int row = wm + m * 16 + l15;
          int byteA = (ks * 128 + h * 64 + lhi * 16) ^ ((row & 7) << 4);
          af[m] = *(const bf16x8*)(Ps + row * 256 + (byteA >> 1));
        }
        int ko = ks * 64 + h * 32 + lhi * 8;
#pragma unroll
        for (int n = 0; n < 4; ++n)
          bf_[n] = *(const bf16x8*)(Bb + (size_t)(wn + n * 16 + l15) * Tc + ko);
#pragma unroll
        for (int m = 0; m < 4; ++m)
#pragma unroll
          for (int n = 0; n < 4; ++n)
            acc[m][n] = __builtin_amdgcn_mfma_f32_16x16x32_bf16(af[m], bf_[n], acc[m][n], 0, 0, 0);
      }
    }
#pragma unroll
    for (int m = 0; m < 4; ++m)
#pragma unroll
      for (int n = 0; n < 4; ++n)
#pragma unroll
        for (int q = 0; q < 4; ++q) {
          int row = wm + m * 16 + lhi * 4 + q;
          int col = wn + n * 16 + l15;
          rd[(size_t)(b * Tc + q0 + row) * Mc + col] = (bf16_t)acc[m][n][q];
        }
  }
}

// ---------------------------------------------------------------- launcher
extern "C" void kernel_launch(void* const* d_in, const int* in_sizes, int n_in,
                              void* d_out, int out_size, void* d_ws, size_t ws_size,
                              hipStream_t stream) {
  const int* idx = (const int*)d_in[0];
  const float* center = (const float*)d_in[1];
  // d_in[2] offset: dead code (x = (b_min+b_max)/2 = center)
  const float* wk = (const float*)d_in[3];
  const float* bk = (const float*)d_in[4];
  const float* wq = (const float*)d_in[5];
  const float* bq = (const float*)d_in[6];
  const float* wv = (const float*)d_in[7];
  const float* bv = (const float*)d_in[8];
  const float* wo = (const float*)d_in[9];
  const float* bo = (const float*)d_in[10];
  const float* wgw = (const float*)d_in[11];
  const float* bgw = (const float*)d_in[12];
  const float* wgf = (const float*)d_in[13];
  const float* bgf = (const float*)d_in[14];
  const float* ln1_g = (const float*)d_in[15];
  const float* ln1_b = (const float*)d_in[16];
  const float* ln2_g = (const float*)d_in[17];
  const float* ln2_b = (const float*)d_in[18];
  const float* w1 = (const float*)d_in[19];
  const float* b1 = (const float*)d_in[20];
  const float* w2 = (const float*)d_in[21];
  const float* b2 = (const float*)d_in[22];
  const float* lnf_g = (const float*)d_in[23];
  const float* lnf_b = (const float*)d_in[24];
  const float* logit_scale = (const float*)d_in[25];

  float* logits = (float*)d_out;                     // [R, V] fp32
  float* states = logits + (size_t)Rc * Vc;          // [L, B, M, M] fp32

  char* p = (char*)d_ws;
  auto alloc = [&](size_t bytes) -> char* {
    char* r = p;
    p += (bytes + 255) & ~(size_t)255;
    return r;
  };
  float* x    = (float*)alloc((size_t)Rc * Dc * 4);
  float* gwb  = (float*)alloc(Rc * 4);
  float* gfb  = (float*)alloc(Rc * 4);
  float* bkqv = (float*)alloc(Lc * 512 * 4);
  float* part = (float*)alloc((size_t)2 * Rc * Dc * 4);   // split-K partials for w2
  bf16_t* xn_bf   = (bf16_t*)alloc((size_t)Rc * Dc * 2);
  bf16_t* h1_bf   = (bf16_t*)alloc((size_t)Rc * Hc * 2);
  bf16_t* k_bf    = (bf16_t*)alloc((size_t)Rc * Mc * 2);
  bf16_t* q_bf    = (bf16_t*)alloc((size_t)Rc * Mc * 2);
  bf16_t* rd_bf   = (bf16_t*)alloc((size_t)Rc * Mc * 2);
  bf16_t* kt_bf   = (bf16_t*)alloc((size_t)Bc * Mc * Tc * 2);
  bf16_t* vt_bf   = (bf16_t*)alloc((size_t)Bc * Mc * Tc * 2);
  bf16_t* cen_bf  = (bf16_t*)alloc((size_t)Vc * Dc * 2);
  bf16_t* w1_bf   = (bf16_t*)alloc((size_t)Lc * Hc * Dc * 2);
  bf16_t* w2_bf   = (bf16_t*)alloc((size_t)Lc * Dc * Hc * 2);
  bf16_t* wo_bf   = (bf16_t*)alloc((size_t)Lc * Dc * Mc * 2);
  bf16_t* wkqv_bf = (bf16_t*)alloc((size_t)Lc * 512 * Dc * 2);

  // merged preamble: cvt + packs + gather/ln1
  pre_k<<<13768, 256, 0, stream>>>(center, cen_bf, w1, w1_bf, w2, w2_bf, wo, wo_bf,
                                   wk, wq, wv, wgw, wgf, wkqv_bf,
                                   bk, bq, bv, bgw, bgf, bkqv,
                                   idx, ln1_g, ln1_b, x, xn_bf);

  const long long zero = 0;
  for (int l = 0; l < Lc; ++l) {
    // kqv GEMM + fused l2norm/transpose/gates epilogue
    kqvprep_k<<<dim3(4, 16), 256, 0, stream>>>(
        xn_bf, wkqv_bf + (size_t)l * 512 * Dc, bkqv + l * 512,
        k_bf, q_bf, kt_bf, vt_bf, gwb, gfb);

    // fused P(decay) + PV + states (in-kernel scan, in-register wgt)
    attn_k<<<dim3(3, Bc), 256, 0, stream>>>(q_bf, k_bf, vt_bf, kt_bf, gwb, gfb,
                                            rd_bf, states + (size_t)l * Bc * Mc * Mc);

    // x += reads @ wo^T + bo
    mms_k<A_NONE, true, false><<<dim3(4, 16, 1), 256, 0, stream>>>(
        rd_bf, wo_bf + (size_t)l * Dc * Mc, x, bo + (size_t)l * Dc,
        Mc, Mc, Mc, Dc, zero, zero, zero);

    ln_k<<<Rc, 64, 0, stream>>>(x, ln2_g + (size_t)l * Dc, ln2_b + (size_t)l * Dc, xn_bf);

    // h1 = gelu(xn @ w1^T + b1) -> bf16
    mms_k<A_GELU, false, true><<<dim3(16, 16, 1), 256, 0, stream>>>(
        xn_bf, w1_bf + (size_t)l * Hc * Dc, h1_bf, b1 + (size_t)l * Hc,
        Dc, Dc, Dc, Hc, zero, zero, zero);

    // w2 split-K=2: partials
    mms_k<A_NONE, false, false><<<dim3(4, 16, 2), 256, 0, stream>>>(
        h1_bf, w2_bf + (size_t)l * Dc * Hc, part, nullptr,
        Hc / 2, Hc, Hc, Dc, (long long)(Hc / 2), (long long)(Hc / 2), (long long)Rc * Dc);

    // x += partials + b2 ; xn = LN(x) with next layer's ln1 (or lnf after last layer)
    const float* ng = (l < Lc - 1) ? ln1_g + (size_t)(l + 1) * Dc : lnf_g;
    const float* nb = (l < Lc - 1) ? ln1_b + (size_t)(l + 1) * Dc : lnf_b;
    redln_k<<<Rc, 64, 0, stream>>>(part, b2 + (size_t)l * Dc, x, ng, nb, xn_bf);
  }

  // logits = (xn @ center^T) * logit_scale/sqrt(512)   (XCD-swizzled, 4000 blocks)
  mm_k<A_NONE, false, true, false, true><<<dim3(250, 16, 1), 256, 0, stream>>>(
      xn_bf, cen_bf, logits, nullptr, Dc, Dc, Dc, Vc, zero, zero, zero,
      logit_scale, 0.044194173824159223f);
}